// Round 20
// baseline (323.891 us; speedup 1.0000x reference)
//
#include <hip/hip_runtime.h>
#include <hip/hip_bf16.h>
#include <math.h>

// ---------------------------------------------------------------------------
// GraphAttentionEmbedding (TGN TransformerConv, H=2, C=64, D=128, EDGE_DIM=256)
//   CSR build: k_zero -> hist -> scan -> fill (perm/srcp/relo)
//   K1 k_node_mfma: staged x-tile in LDS, W in registers; q/k/v/skip ALL bf16
//   K2 k_edge_mfma v4: ORIGINAL-edge-order staged GEMM, 4-wave blocks,
//      2 m-subtiles per wave (every B ds_read feeds 2 MFMAs), cvt_pk convs.
//   K3 k_agg v3: perm-gathered e rows (slot binding consumed in ONE kernel --
//      R6/R19 proved cross-kernel slot-binding diverges under graph replay),
//      hoisted shfl, predicated loads, write-only output.
//   [R20 = revert to R18, the verified best: 322.8 us]
// ---------------------------------------------------------------------------

#define SCALE_ATTN 0.125f
#define SCAN_CHUNK 512

typedef __attribute__((ext_vector_type(8))) short bf16x8;
typedef __attribute__((ext_vector_type(4))) float f32x4;

union AFrag { bf16x8 v; unsigned int w[4]; unsigned short u[8]; };

__device__ __forceinline__ unsigned short f2bf(float f) {
    __hip_bfloat16 h = __float2bfloat16(f);
    unsigned short u;
    __builtin_memcpy(&u, &h, 2);
    return u;
}
__device__ __forceinline__ unsigned int f2bf2(float lo, float hi) {
    __hip_bfloat162 h2 = __float22bfloat162_rn(float2{lo, hi});
    unsigned int u;
    __builtin_memcpy(&u, &h2, 4);
    return u;
}
__device__ __forceinline__ float bf2f(unsigned int lo16) {
    return __uint_as_float(lo16 << 16);
}
__device__ __forceinline__ void unpack8(uint4 u, float* f) {
    f[0] = bf2f(u.x & 0xffffu); f[1] = bf2f(u.x >> 16);
    f[2] = bf2f(u.y & 0xffffu); f[3] = bf2f(u.y >> 16);
    f[4] = bf2f(u.z & 0xffffu); f[5] = bf2f(u.z >> 16);
    f[6] = bf2f(u.w & 0xffffu); f[7] = bf2f(u.w >> 16);
}
__device__ __forceinline__ bf16x8 pack2(float4 a, float4 b) {
    AFrag f;
    f.w[0] = f2bf2(a.x, a.y);
    f.w[1] = f2bf2(a.z, a.w);
    f.w[2] = f2bf2(b.x, b.y);
    f.w[3] = f2bf2(b.z, b.w);
    return f.v;
}

__global__ __launch_bounds__(256) void k_zero(int4* __restrict__ p, int n4)
{
    const int i = blockIdx.x * 256 + threadIdx.x;
    if (i < n4) p[i] = make_int4(0, 0, 0, 0);
}

// ---------------------------------------------------------------------------
// K1: all four node linears in ONE kernel. Block=512 (8 waves), tile=32 nodes.
// LDS: x-tile bf16 [32][128] swizzled (8 KB). Wave w owns 64 cols of the 512
// concatenated outputs (mat = w>>1: q,k,v,skip; half = w&1). ALL outputs bf16.
// ---------------------------------------------------------------------------
__global__ __launch_bounds__(512, 4) void k_node_mfma(
    const float4* __restrict__ x4,
    const float* __restrict__ Wq, const float* __restrict__ Wk,
    const float* __restrict__ Wv, const float* __restrict__ Ws,
    const float* __restrict__ bq, const float* __restrict__ bk,
    const float* __restrict__ bv, const float* __restrict__ bs,
    unsigned short* __restrict__ qb, unsigned short* __restrict__ kb,
    unsigned short* __restrict__ vb, unsigned short* __restrict__ skb,
    int N, int numTiles)
{
    __shared__ __align__(16) unsigned short sX[32 * 128];   // 8 KB
    const int tid = threadIdx.x;
    const int w = tid >> 6, l = tid & 63;
    const int l15 = l & 15, lg = l >> 4;
    const int mat = w >> 1;                 // 0 q, 1 k, 2 v, 3 skip
    const int colbase = (w & 1) * 64;       // within the 128-col matrix

    const float* Wm = (mat == 0) ? Wq : (mat == 1) ? Wk : (mat == 2) ? Wv : Ws;
    const float* bm = (mat == 0) ? bq : (mat == 1) ? bk : (mat == 2) ? bv : bs;
    unsigned short* dst = (mat == 0) ? qb : (mat == 1) ? kb : (mat == 2) ? vb : skb;

    bf16x8 Bf[4][4];
    float bias[4];
    #pragma unroll
    for (int nt = 0; nt < 4; ++nt) {
        const int col = colbase + nt * 16 + l15;
        bias[nt] = bm[col];
        #pragma unroll
        for (int ks = 0; ks < 4; ++ks) {
            AFrag f;
            #pragma unroll
            for (int j = 0; j < 4; ++j)
                f.w[j] = f2bf2(Wm[(ks * 32 + lg * 8 + j * 2) * 128 + col],
                               Wm[(ks * 32 + lg * 8 + j * 2 + 1) * 128 + col]);
            Bf[ks][nt] = f.v;
        }
    }

    for (int tile = blockIdx.x; tile < numTiles; tile += gridDim.x) {
        {
            const int e = tid >> 4, k8 = tid & 15;
            const int row = min(tile * 32 + e, N - 1);
            const float4 a0 = x4[(size_t)row * 32 + k8 * 2];
            const float4 a1 = x4[(size_t)row * 32 + k8 * 2 + 1];
            const int byteoff = (e * 256 + k8 * 16) ^ ((e & 7) << 4);
            *(bf16x8*)((char*)sX + byteoff) = pack2(a0, a1);
        }
        __syncthreads();

        f32x4 acc[2][4];
        #pragma unroll
        for (int m = 0; m < 2; ++m)
            #pragma unroll
            for (int nt = 0; nt < 4; ++nt) acc[m][nt] = (f32x4)(0.f);

        #pragma unroll
        for (int m = 0; m < 2; ++m) {
            const int lrow = m * 16 + l15;
            #pragma unroll
            for (int ks = 0; ks < 4; ++ks) {
                const int byteoff = (lrow * 256 + ks * 64 + lg * 16) ^ ((lrow & 7) << 4);
                const bf16x8 a = *(const bf16x8*)((const char*)sX + byteoff);
                #pragma unroll
                for (int nt = 0; nt < 4; ++nt)
                    acc[m][nt] = __builtin_amdgcn_mfma_f32_16x16x32_bf16(a, Bf[ks][nt], acc[m][nt], 0, 0, 0);
            }
        }

        #pragma unroll
        for (int m = 0; m < 2; ++m) {
            #pragma unroll
            for (int nt = 0; nt < 4; ++nt) {
                const int col = colbase + nt * 16 + l15;
                #pragma unroll
                for (int r = 0; r < 4; ++r) {
                    const int node = tile * 32 + m * 16 + lg * 4 + r;
                    if (node < N)
                        dst[(size_t)node * 128 + col] = f2bf(acc[m][nt][r] + bias[nt]);
                }
            }
        }
        __syncthreads();
    }
}

// ---------------------------------------------------------------------------
// K2 v4: staged edge GEMM with B-reuse. Block=256 (4 waves), tile = 64 edges.
// LDS: sWe 64 KB + sMsg 16 KB = 80 KB -> 2 blocks/CU.
// Wave w: colhalf ch = w&1 (64 cols), mpair mp = w>>1 -> m-subtiles
// {2mp, 2mp+1}. Every B ds_read feeds TWO MFMAs. Conversions via cvt_pk.
// All reads AND writes in ORIGINAL edge order (replay-safe).
// ---------------------------------------------------------------------------
__global__ __launch_bounds__(256, 2) void k_edge_mfma(
    const float4* __restrict__ msg4,
    const float* __restrict__ relo,
    const float4* __restrict__ tw4, const float4* __restrict__ tb4,
    const float* __restrict__ We,
    unsigned short* __restrict__ ebuf, int E, int numTiles)
{
    __shared__ __align__(16) unsigned short sWe[128 * 256];   // 64 KB
    __shared__ __align__(16) unsigned short sMsg[64 * 128];   // 16 KB
    const int tid = threadIdx.x;
    const int w = tid >> 6, l = tid & 63;
    const int l15 = l & 15, lg = l >> 4;
    const int ch = w & 1;                 // col half: cols ch*64 .. +63
    const int mp = w >> 1;                // m-pair: rows mp*32 .. +31

    for (int c = tid; c < 4096; c += 256) {
        const int n = c >> 5, k0 = (c & 31) << 3;
        AFrag af;
        #pragma unroll
        for (int j = 0; j < 4; ++j)
            af.w[j] = f2bf2(We[(k0 + j * 2) * 128 + n], We[(k0 + j * 2 + 1) * 128 + n]);
        const int byteoff = ((n << 9) + (k0 << 1)) ^ ((n & 7) << 4);
        *(bf16x8*)((char*)sWe + byteoff) = af.v;
    }
    __syncthreads();

    for (int tile = blockIdx.x; tile < numTiles; tile += gridDim.x) {
        const int ebase = tile * 64;

        // ---- stage msg tile (64 e x 16 units), coalesced, swizzled
        #pragma unroll
        for (int i = 0; i < 4; ++i) {
            const int U = tid + i * 256;                 // 0..1023
            const int e = U >> 4, u = U & 15;
            const int er = min(ebase + e, E - 1);
            const float4 a0 = msg4[(size_t)er * 32 + u * 2];
            const float4 a1 = msg4[(size_t)er * 32 + u * 2 + 1];
            const int byteoff = (e << 8) + ((u ^ (e & 7)) << 4);
            *(bf16x8*)((char*)sMsg + byteoff) = pack2(a0, a1);
        }
        __syncthreads();

        // ---- compute: 2 m-subtiles per wave
        const int r0 = mp * 32 + l15;                    // rows of subtile 0
        const int r1 = r0 + 16;                          // rows of subtile 1
        const float rel0 = relo[min(ebase + r0, E - 1)];
        const float rel1 = relo[min(ebase + r1, E - 1)];

        f32x4 acc0[4], acc1[4];
        #pragma unroll
        for (int i = 0; i < 4; ++i) { acc0[i] = (f32x4)(0.f); acc1[i] = (f32x4)(0.f); }

        #pragma unroll
        for (int kk = 0; kk < 4; ++kk) {
            const int kbase = (kk << 5) + (lg << 3);     // bf16 k index

            // cos A-frags for both subtiles (VALU; packed cvt)
            const float4 tww = tw4[kbase >> 2];
            const float4 tw2 = tw4[(kbase >> 2) + 1];
            const float4 tbb = tb4[kbase >> 2];
            const float4 tb2 = tb4[(kbase >> 2) + 1];
            AFrag a0, a1;
            a0.w[0] = f2bf2(__cosf(fmaf(rel0, tww.x, tbb.x)),
                            __cosf(fmaf(rel0, tww.y, tbb.y)));
            a0.w[1] = f2bf2(__cosf(fmaf(rel0, tww.z, tbb.z)),
                            __cosf(fmaf(rel0, tww.w, tbb.w)));
            a0.w[2] = f2bf2(__cosf(fmaf(rel0, tw2.x, tb2.x)),
                            __cosf(fmaf(rel0, tw2.y, tb2.y)));
            a0.w[3] = f2bf2(__cosf(fmaf(rel0, tw2.z, tb2.z)),
                            __cosf(fmaf(rel0, tw2.w, tb2.w)));
            a1.w[0] = f2bf2(__cosf(fmaf(rel1, tww.x, tbb.x)),
                            __cosf(fmaf(rel1, tww.y, tbb.y)));
            a1.w[1] = f2bf2(__cosf(fmaf(rel1, tww.z, tbb.z)),
                            __cosf(fmaf(rel1, tww.w, tbb.w)));
            a1.w[2] = f2bf2(__cosf(fmaf(rel1, tw2.x, tb2.x)),
                            __cosf(fmaf(rel1, tw2.y, tb2.y)));
            a1.w[3] = f2bf2(__cosf(fmaf(rel1, tw2.z, tb2.z)),
                            __cosf(fmaf(rel1, tw2.w, tb2.w)));

            // msg A-frags for both subtiles (LDS, swizzled)
            const int mu = (kk << 2) + lg;
            const bf16x8 am0 = *(const bf16x8*)((const char*)sMsg +
                                 ((r0 << 8) + ((mu ^ (r0 & 7)) << 4)));
            const bf16x8 am1 = *(const bf16x8*)((const char*)sMsg +
                                 ((r1 << 8) + ((mu ^ (r1 & 7)) << 4)));

            // B reads shared by both subtiles
            #pragma unroll
            for (int nt = 0; nt < 4; ++nt) {
                const int nrow = ch * 64 + nt * 16 + l15;
                const int swz = (nrow & 7) << 4;
                const bf16x8 bC = *(const bf16x8*)((const char*)sWe +
                                   (((nrow << 9) + (kbase << 1)) ^ swz));
                acc0[nt] = __builtin_amdgcn_mfma_f32_16x16x32_bf16(a0.v, bC, acc0[nt], 0, 0, 0);
                acc1[nt] = __builtin_amdgcn_mfma_f32_16x16x32_bf16(a1.v, bC, acc1[nt], 0, 0, 0);
                const bf16x8 bM = *(const bf16x8*)((const char*)sWe +
                                   (((nrow << 9) + ((128 + kbase) << 1)) ^ swz));
                acc0[nt] = __builtin_amdgcn_mfma_f32_16x16x32_bf16(am0, bM, acc0[nt], 0, 0, 0);
                acc1[nt] = __builtin_amdgcn_mfma_f32_16x16x32_bf16(am1, bM, acc1[nt], 0, 0, 0);
            }
        }

        // ---- epilogue: sequential edge rows (coverage by construction)
        #pragma unroll
        for (int nt = 0; nt < 4; ++nt) {
            const int col = ch * 64 + nt * 16 + l15;
            #pragma unroll
            for (int r = 0; r < 4; ++r) {
                const int e0 = ebase + mp * 32 + (lg << 2) + r;
                const int e1 = e0 + 16;
                if (e0 < E) ebuf[(size_t)e0 * 128 + col] = f2bf(acc0[nt][r]);
                if (e1 < E) ebuf[(size_t)e1 * 128 + col] = f2bf(acc1[nt][r]);
            }
        }
        __syncthreads();   // before next tile's stage overwrites sMsg
    }
}

// ---------------------------------------------------------------------------
// CSR build
// ---------------------------------------------------------------------------
__global__ __launch_bounds__(256) void k_hist(
    const int* __restrict__ ei, int* __restrict__ counts, int E)
{
    int i = blockIdx.x * 256 + threadIdx.x;
    if (i < E) atomicAdd(&counts[ei[E + i]], 1);
}

__global__ __launch_bounds__(256) void k_scan_partial(
    const int* __restrict__ counts, int* __restrict__ partial, int N)
{
    const int base = blockIdx.x * SCAN_CHUNK;
    int v = 0;
    for (int i = threadIdx.x; i < SCAN_CHUNK; i += 256) {
        const int idx = base + i;
        if (idx < N) v += counts[idx];
    }
    __shared__ int red[4];
    #pragma unroll
    for (int off = 1; off < 64; off <<= 1) v += __shfl_xor(v, off);
    if ((threadIdx.x & 63) == 0) red[threadIdx.x >> 6] = v;
    __syncthreads();
    if (threadIdx.x == 0) partial[blockIdx.x] = red[0] + red[1] + red[2] + red[3];
}

__global__ __launch_bounds__(256) void k_scan_base(
    const int* __restrict__ partial, int* __restrict__ base, int nb)
{
    __shared__ int tmp[256];
    const int v = (threadIdx.x < nb) ? partial[threadIdx.x] : 0;
    tmp[threadIdx.x] = v;
    __syncthreads();
    for (int off = 1; off < 256; off <<= 1) {
        const int add = (threadIdx.x >= off) ? tmp[threadIdx.x - off] : 0;
        __syncthreads();
        tmp[threadIdx.x] += add;
        __syncthreads();
    }
    if (threadIdx.x < nb) base[threadIdx.x] = tmp[threadIdx.x] - v;
}

__global__ __launch_bounds__(256) void k_scan_final(
    const int* __restrict__ counts, const int* __restrict__ base,
    int* __restrict__ rowptr, int* __restrict__ cursor, int N)
{
    const int i0 = blockIdx.x * SCAN_CHUNK;
    __shared__ int tmp[256];
    const int ia = i0 + threadIdx.x * 2, ib = ia + 1;
    const int v0 = (ia < N) ? counts[ia] : 0;
    const int v1 = (ib < N) ? counts[ib] : 0;
    const int s = v0 + v1;
    tmp[threadIdx.x] = s;
    __syncthreads();
    for (int off = 1; off < 256; off <<= 1) {
        const int add = (threadIdx.x >= off) ? tmp[threadIdx.x - off] : 0;
        __syncthreads();
        tmp[threadIdx.x] += add;
        __syncthreads();
    }
    const int excl = tmp[threadIdx.x] - s + base[blockIdx.x];
    if (ia < N) { rowptr[ia] = excl;      cursor[ia] = excl; }
    if (ib < N) { rowptr[ib] = excl + v0; cursor[ib] = excl + v0; }
}

__global__ __launch_bounds__(256) void k_fill(
    const int* __restrict__ ei, const float* __restrict__ t,
    const float* __restrict__ lu, int* __restrict__ cursor,
    int* __restrict__ perm, int* __restrict__ srcp,
    float* __restrict__ relo, int E)
{
    int i = blockIdx.x * 256 + threadIdx.x;
    if (i < E) {
        const int s = ei[i];
        const int d = ei[E + i];
        const int pos = atomicAdd(&cursor[d], 1);
        perm[pos] = i;
        srcp[pos] = s;
        relo[i] = t[i] - lu[s];
    }
}

// ---------------------------------------------------------------------------
// K3 v3: fused aggregation. One wave per dst. Lane = (eg = l>>4 edge group,
// s16 = l&15). 4 edges/iter. SHFL RUNS WITH ALL LANES ACTIVE (clamped index);
// only the loads+math are predicated (uniform per 16-lane group).
// Output write-only: skip from bf16 skb. e rows gathered via perm (the
// slot->edge binding is consumed ONLY here -- replay-safe).
// ---------------------------------------------------------------------------
__global__ __launch_bounds__(256) void k_agg(
    const int* __restrict__ srcp, const int* __restrict__ perm,
    const int* __restrict__ rowptr, const int* __restrict__ counts,
    const uint4* __restrict__ qb4, const uint4* __restrict__ kb4,
    const uint4* __restrict__ vb4, const uint4* __restrict__ eb4,
    const uint4* __restrict__ skb4, float4* __restrict__ out4, int N)
{
    const int d = blockIdx.x * 4 + (threadIdx.x >> 6);
    if (d >= N) return;
    const int l = threadIdx.x & 63;
    const int s16 = l & 15;       // 16B slot (8 channels)
    const int eg = l >> 4;        // edge group 0..3
    const int start = rowptr[d];
    const int deg = counts[d];

    float qf[8];
    unpack8(qb4[(size_t)d * 16 + s16], qf);
    float accf[8] = {0.f, 0.f, 0.f, 0.f, 0.f, 0.f, 0.f, 0.f};
    float denom = 0.f;

    for (int cbase = 0; cbase < deg; cbase += 64) {
        const int clen = min(deg - cbase, 64);
        int mySrc = 0, myEid = 0;
        if (l < clen) {
            mySrc = srcp[start + cbase + l];   // coalesced
            myEid = perm[start + cbase + l];   // coalesced
        }

        #pragma unroll 2
        for (int i = 0; i < clen; i += 4) {
            const int off = i + eg;
            const bool valid = off < clen;
            const int offc = valid ? off : 0;
            // shfl with ALL lanes active (ds_bpermute from inactive source
            // lanes is undefined -- the R13 bug)
            const int src = __shfl(mySrc, offc);
            const int eid = __shfl(myEid, offc);
            if (valid) {                       // uniform per 16-lane group
                float kf[8], ef[8], vf[8];
                unpack8(kb4[(size_t)src * 16 + s16], kf);
                unpack8(eb4[(size_t)eid * 16 + s16], ef);
                unpack8(vb4[(size_t)src * 16 + s16], vf);
                float s = 0.f;
                #pragma unroll
                for (int j = 0; j < 8; ++j) s = fmaf(qf[j], kf[j] + ef[j], s);
                s += __shfl_xor(s, 1);
                s += __shfl_xor(s, 2);
                s += __shfl_xor(s, 4);
                const float p = __expf(s * SCALE_ATTN);
                denom += p;
                #pragma unroll
                for (int j = 0; j < 8; ++j) accf[j] = fmaf(p, vf[j] + ef[j], accf[j]);
            }
        }
    }
    #pragma unroll
    for (int j = 0; j < 8; ++j) {
        accf[j] += __shfl_xor(accf[j], 16);
        accf[j] += __shfl_xor(accf[j], 32);
    }
    denom += __shfl_xor(denom, 16);
    denom += __shfl_xor(denom, 32);

    if (l < 16) {
        const float inv = 1.f / (denom + 1e-16f);
        float sk[8];
        unpack8(skb4[(size_t)d * 16 + s16], sk);
        float4* o = out4 + (size_t)d * 32 + s16 * 2;
        o[0] = make_float4(fmaf(accf[0], inv, sk[0]), fmaf(accf[1], inv, sk[1]),
                           fmaf(accf[2], inv, sk[2]), fmaf(accf[3], inv, sk[3]));
        o[1] = make_float4(fmaf(accf[4], inv, sk[4]), fmaf(accf[5], inv, sk[5]),
                           fmaf(accf[6], inv, sk[6]), fmaf(accf[7], inv, sk[7]));
    }
}

// ---------------------------------------------------------------------------
extern "C" void kernel_launch(void* const* d_in, const int* in_sizes, int n_in,
                              void* d_out, int out_size, void* d_ws, size_t ws_size,
                              hipStream_t stream)
{
    const float* x   = (const float*)d_in[0];
    const float* lu  = (const float*)d_in[1];
    const int*   ei  = (const int*)d_in[2];
    const float* t   = (const float*)d_in[3];
    const float* msg = (const float*)d_in[4];
    const float* tw  = (const float*)d_in[5];
    const float* tb  = (const float*)d_in[6];
    const float* Wq  = (const float*)d_in[7];
    const float* bq  = (const float*)d_in[8];
    const float* Wk  = (const float*)d_in[9];
    const float* bk  = (const float*)d_in[10];
    const float* Wv  = (const float*)d_in[11];
    const float* bv  = (const float*)d_in[12];
    const float* We  = (const float*)d_in[13];
    const float* Wsk = (const float*)d_in[14];
    const float* bsk = (const float*)d_in[15];

    const int N = in_sizes[1];   // last_update: N elements
    const int E = in_sizes[3];   // t: E elements
    float* out = (float*)d_out;

    char* ws = (char*)d_ws;
    unsigned short* qb  = (unsigned short*)ws;  ws += (size_t)N * 128 * sizeof(unsigned short);
    unsigned short* kb  = (unsigned short*)ws;  ws += (size_t)N * 128 * sizeof(unsigned short);
    unsigned short* vb  = (unsigned short*)ws;  ws += (size_t)N * 128 * sizeof(unsigned short);
    unsigned short* skb = (unsigned short*)ws;  ws += (size_t)N * 128 * sizeof(unsigned short);
    unsigned short* eb  = (unsigned short*)ws;  ws += (size_t)E * 128 * sizeof(unsigned short);
    int*   counts  = (int*)ws;   ws += (size_t)N * sizeof(int);
    int*   rowptr  = (int*)ws;   ws += (size_t)N * sizeof(int);
    int*   cursor  = (int*)ws;   ws += (size_t)N * sizeof(int);
    int*   perm    = (int*)ws;   ws += (size_t)E * sizeof(int);
    int*   srcp    = (int*)ws;   ws += (size_t)E * sizeof(int);
    float* relo    = (float*)ws; ws += (size_t)E * sizeof(float);
    int*   partial = (int*)ws;   ws += 512 * sizeof(int);
    int*   baseArr = (int*)ws;   ws += 512 * sizeof(int);

    const int nScan = (N + SCAN_CHUNK - 1) / SCAN_CHUNK;

    const int n4 = (N + 3) / 4;
    k_zero<<<(n4 + 255) / 256, 256, 0, stream>>>((int4*)counts, n4);

    // CSR build
    k_hist<<<(E + 255) / 256, 256, 0, stream>>>(ei, counts, E);
    k_scan_partial<<<nScan, 256, 0, stream>>>(counts, partial, N);
    k_scan_base<<<1, 256, 0, stream>>>(partial, baseArr, nScan);
    k_scan_final<<<nScan, 256, 0, stream>>>(counts, baseArr, rowptr, cursor, N);
    k_fill<<<(E + 255) / 256, 256, 0, stream>>>(ei, t, lu, cursor, perm, srcp, relo, E);

    // node linears: q/k/v/skip (all bf16) in ONE staged-x launch
    const int nTN = (N + 31) / 32;
    k_node_mfma<<<min(nTN, 1024), 512, 0, stream>>>(
        (const float4*)x, Wq, Wk, Wv, Wsk, bq, bk, bv, bsk,
        qb, kb, vb, skb, N, nTN);

    // edge GEMM v4: 64-edge tiles, 4-wave blocks, B-reuse x2
    const int nTE = (E + 63) / 64;
    k_edge_mfma<<<min(nTE, 512), 256, 0, stream>>>(
        (const float4*)msg, relo,
        (const float4*)tw, (const float4*)tb, We, eb, E, nTE);

    // fused aggregation (predicated loads, hoisted shfl, write-only output)
    k_agg<<<(N + 3) / 4, 256, 0, stream>>>(
        srcp, perm, rowptr, counts,
        (const uint4*)qb, (const uint4*)kb, (const uint4*)vb, (const uint4*)eb,
        (const uint4*)skb, (float4*)out, N);
}

// Round 21
// 314.692 us; speedup vs baseline: 1.0292x; 1.0292x over previous
//
#include <hip/hip_runtime.h>
#include <hip/hip_bf16.h>
#include <math.h>

// ---------------------------------------------------------------------------
// GraphAttentionEmbedding (TGN TransformerConv, H=2, C=64, D=128, EDGE_DIM=256)
//   CSR build: k_zero -> hist -> scan -> fill (perm/srcp/relo)
//   K1 k_node_mfma: staged x-tile in LDS, W in registers; q/k/v/skip ALL bf16
//   K2 k_edge_mfma v4: ORIGINAL-edge-order staged GEMM, 4-wave blocks,
//      2 m-subtiles per wave (every B ds_read feeds 2 MFMAs), cvt_pk convs.
//   K3 k_agg v5: TWO dst per wave (32-lane half each, 2 edge groups of 16).
//      Mean deg=5 -> tail utilization 62% -> 83%; iterations/dst ~2 -> ~1.5.
//      Head-local logit reduce unchanged (xor 1,2,4 in 8-lane head slices);
//      cross-group combine = single xor16; shfl half-local, sources active.
// ---------------------------------------------------------------------------

#define SCALE_ATTN 0.125f
#define SCAN_CHUNK 512

typedef __attribute__((ext_vector_type(8))) short bf16x8;
typedef __attribute__((ext_vector_type(4))) float f32x4;

union AFrag { bf16x8 v; unsigned int w[4]; unsigned short u[8]; };

__device__ __forceinline__ unsigned short f2bf(float f) {
    __hip_bfloat16 h = __float2bfloat16(f);
    unsigned short u;
    __builtin_memcpy(&u, &h, 2);
    return u;
}
__device__ __forceinline__ unsigned int f2bf2(float lo, float hi) {
    __hip_bfloat162 h2 = __float22bfloat162_rn(float2{lo, hi});
    unsigned int u;
    __builtin_memcpy(&u, &h2, 4);
    return u;
}
__device__ __forceinline__ float bf2f(unsigned int lo16) {
    return __uint_as_float(lo16 << 16);
}
__device__ __forceinline__ void unpack8(uint4 u, float* f) {
    f[0] = bf2f(u.x & 0xffffu); f[1] = bf2f(u.x >> 16);
    f[2] = bf2f(u.y & 0xffffu); f[3] = bf2f(u.y >> 16);
    f[4] = bf2f(u.z & 0xffffu); f[5] = bf2f(u.z >> 16);
    f[6] = bf2f(u.w & 0xffffu); f[7] = bf2f(u.w >> 16);
}
__device__ __forceinline__ bf16x8 pack2(float4 a, float4 b) {
    AFrag f;
    f.w[0] = f2bf2(a.x, a.y);
    f.w[1] = f2bf2(a.z, a.w);
    f.w[2] = f2bf2(b.x, b.y);
    f.w[3] = f2bf2(b.z, b.w);
    return f.v;
}

__global__ __launch_bounds__(256) void k_zero(int4* __restrict__ p, int n4)
{
    const int i = blockIdx.x * 256 + threadIdx.x;
    if (i < n4) p[i] = make_int4(0, 0, 0, 0);
}

// ---------------------------------------------------------------------------
// K1: all four node linears in ONE kernel. Block=512 (8 waves), tile=32 nodes.
// ---------------------------------------------------------------------------
__global__ __launch_bounds__(512, 4) void k_node_mfma(
    const float4* __restrict__ x4,
    const float* __restrict__ Wq, const float* __restrict__ Wk,
    const float* __restrict__ Wv, const float* __restrict__ Ws,
    const float* __restrict__ bq, const float* __restrict__ bk,
    const float* __restrict__ bv, const float* __restrict__ bs,
    unsigned short* __restrict__ qb, unsigned short* __restrict__ kb,
    unsigned short* __restrict__ vb, unsigned short* __restrict__ skb,
    int N, int numTiles)
{
    __shared__ __align__(16) unsigned short sX[32 * 128];   // 8 KB
    const int tid = threadIdx.x;
    const int w = tid >> 6, l = tid & 63;
    const int l15 = l & 15, lg = l >> 4;
    const int mat = w >> 1;                 // 0 q, 1 k, 2 v, 3 skip
    const int colbase = (w & 1) * 64;       // within the 128-col matrix

    const float* Wm = (mat == 0) ? Wq : (mat == 1) ? Wk : (mat == 2) ? Wv : Ws;
    const float* bm = (mat == 0) ? bq : (mat == 1) ? bk : (mat == 2) ? bv : bs;
    unsigned short* dst = (mat == 0) ? qb : (mat == 1) ? kb : (mat == 2) ? vb : skb;

    bf16x8 Bf[4][4];
    float bias[4];
    #pragma unroll
    for (int nt = 0; nt < 4; ++nt) {
        const int col = colbase + nt * 16 + l15;
        bias[nt] = bm[col];
        #pragma unroll
        for (int ks = 0; ks < 4; ++ks) {
            AFrag f;
            #pragma unroll
            for (int j = 0; j < 4; ++j)
                f.w[j] = f2bf2(Wm[(ks * 32 + lg * 8 + j * 2) * 128 + col],
                               Wm[(ks * 32 + lg * 8 + j * 2 + 1) * 128 + col]);
            Bf[ks][nt] = f.v;
        }
    }

    for (int tile = blockIdx.x; tile < numTiles; tile += gridDim.x) {
        {
            const int e = tid >> 4, k8 = tid & 15;
            const int row = min(tile * 32 + e, N - 1);
            const float4 a0 = x4[(size_t)row * 32 + k8 * 2];
            const float4 a1 = x4[(size_t)row * 32 + k8 * 2 + 1];
            const int byteoff = (e * 256 + k8 * 16) ^ ((e & 7) << 4);
            *(bf16x8*)((char*)sX + byteoff) = pack2(a0, a1);
        }
        __syncthreads();

        f32x4 acc[2][4];
        #pragma unroll
        for (int m = 0; m < 2; ++m)
            #pragma unroll
            for (int nt = 0; nt < 4; ++nt) acc[m][nt] = (f32x4)(0.f);

        #pragma unroll
        for (int m = 0; m < 2; ++m) {
            const int lrow = m * 16 + l15;
            #pragma unroll
            for (int ks = 0; ks < 4; ++ks) {
                const int byteoff = (lrow * 256 + ks * 64 + lg * 16) ^ ((lrow & 7) << 4);
                const bf16x8 a = *(const bf16x8*)((const char*)sX + byteoff);
                #pragma unroll
                for (int nt = 0; nt < 4; ++nt)
                    acc[m][nt] = __builtin_amdgcn_mfma_f32_16x16x32_bf16(a, Bf[ks][nt], acc[m][nt], 0, 0, 0);
            }
        }

        #pragma unroll
        for (int m = 0; m < 2; ++m) {
            #pragma unroll
            for (int nt = 0; nt < 4; ++nt) {
                const int col = colbase + nt * 16 + l15;
                #pragma unroll
                for (int r = 0; r < 4; ++r) {
                    const int node = tile * 32 + m * 16 + lg * 4 + r;
                    if (node < N)
                        dst[(size_t)node * 128 + col] = f2bf(acc[m][nt][r] + bias[nt]);
                }
            }
        }
        __syncthreads();
    }
}

// ---------------------------------------------------------------------------
// K2 v4: staged edge GEMM with B-reuse. Block=256 (4 waves), tile = 64 edges.
// All reads AND writes in ORIGINAL edge order (replay-safe).
// ---------------------------------------------------------------------------
__global__ __launch_bounds__(256, 2) void k_edge_mfma(
    const float4* __restrict__ msg4,
    const float* __restrict__ relo,
    const float4* __restrict__ tw4, const float4* __restrict__ tb4,
    const float* __restrict__ We,
    unsigned short* __restrict__ ebuf, int E, int numTiles)
{
    __shared__ __align__(16) unsigned short sWe[128 * 256];   // 64 KB
    __shared__ __align__(16) unsigned short sMsg[64 * 128];   // 16 KB
    const int tid = threadIdx.x;
    const int w = tid >> 6, l = tid & 63;
    const int l15 = l & 15, lg = l >> 4;
    const int ch = w & 1;                 // col half: cols ch*64 .. +63
    const int mp = w >> 1;                // m-pair: rows mp*32 .. +31

    for (int c = tid; c < 4096; c += 256) {
        const int n = c >> 5, k0 = (c & 31) << 3;
        AFrag af;
        #pragma unroll
        for (int j = 0; j < 4; ++j)
            af.w[j] = f2bf2(We[(k0 + j * 2) * 128 + n], We[(k0 + j * 2 + 1) * 128 + n]);
        const int byteoff = ((n << 9) + (k0 << 1)) ^ ((n & 7) << 4);
        *(bf16x8*)((char*)sWe + byteoff) = af.v;
    }
    __syncthreads();

    for (int tile = blockIdx.x; tile < numTiles; tile += gridDim.x) {
        const int ebase = tile * 64;

        #pragma unroll
        for (int i = 0; i < 4; ++i) {
            const int U = tid + i * 256;                 // 0..1023
            const int e = U >> 4, u = U & 15;
            const int er = min(ebase + e, E - 1);
            const float4 a0 = msg4[(size_t)er * 32 + u * 2];
            const float4 a1 = msg4[(size_t)er * 32 + u * 2 + 1];
            const int byteoff = (e << 8) + ((u ^ (e & 7)) << 4);
            *(bf16x8*)((char*)sMsg + byteoff) = pack2(a0, a1);
        }
        __syncthreads();

        const int r0 = mp * 32 + l15;                    // rows of subtile 0
        const int r1 = r0 + 16;                          // rows of subtile 1
        const float rel0 = relo[min(ebase + r0, E - 1)];
        const float rel1 = relo[min(ebase + r1, E - 1)];

        f32x4 acc0[4], acc1[4];
        #pragma unroll
        for (int i = 0; i < 4; ++i) { acc0[i] = (f32x4)(0.f); acc1[i] = (f32x4)(0.f); }

        #pragma unroll
        for (int kk = 0; kk < 4; ++kk) {
            const int kbase = (kk << 5) + (lg << 3);     // bf16 k index

            const float4 tww = tw4[kbase >> 2];
            const float4 tw2 = tw4[(kbase >> 2) + 1];
            const float4 tbb = tb4[kbase >> 2];
            const float4 tb2 = tb4[(kbase >> 2) + 1];
            AFrag a0, a1;
            a0.w[0] = f2bf2(__cosf(fmaf(rel0, tww.x, tbb.x)),
                            __cosf(fmaf(rel0, tww.y, tbb.y)));
            a0.w[1] = f2bf2(__cosf(fmaf(rel0, tww.z, tbb.z)),
                            __cosf(fmaf(rel0, tww.w, tbb.w)));
            a0.w[2] = f2bf2(__cosf(fmaf(rel0, tw2.x, tb2.x)),
                            __cosf(fmaf(rel0, tw2.y, tb2.y)));
            a0.w[3] = f2bf2(__cosf(fmaf(rel0, tw2.z, tb2.z)),
                            __cosf(fmaf(rel0, tw2.w, tb2.w)));
            a1.w[0] = f2bf2(__cosf(fmaf(rel1, tww.x, tbb.x)),
                            __cosf(fmaf(rel1, tww.y, tbb.y)));
            a1.w[1] = f2bf2(__cosf(fmaf(rel1, tww.z, tbb.z)),
                            __cosf(fmaf(rel1, tww.w, tbb.w)));
            a1.w[2] = f2bf2(__cosf(fmaf(rel1, tw2.x, tb2.x)),
                            __cosf(fmaf(rel1, tw2.y, tb2.y)));
            a1.w[3] = f2bf2(__cosf(fmaf(rel1, tw2.z, tb2.z)),
                            __cosf(fmaf(rel1, tw2.w, tb2.w)));

            const int mu = (kk << 2) + lg;
            const bf16x8 am0 = *(const bf16x8*)((const char*)sMsg +
                                 ((r0 << 8) + ((mu ^ (r0 & 7)) << 4)));
            const bf16x8 am1 = *(const bf16x8*)((const char*)sMsg +
                                 ((r1 << 8) + ((mu ^ (r1 & 7)) << 4)));

            #pragma unroll
            for (int nt = 0; nt < 4; ++nt) {
                const int nrow = ch * 64 + nt * 16 + l15;
                const int swz = (nrow & 7) << 4;
                const bf16x8 bC = *(const bf16x8*)((const char*)sWe +
                                   (((nrow << 9) + (kbase << 1)) ^ swz));
                acc0[nt] = __builtin_amdgcn_mfma_f32_16x16x32_bf16(a0.v, bC, acc0[nt], 0, 0, 0);
                acc1[nt] = __builtin_amdgcn_mfma_f32_16x16x32_bf16(a1.v, bC, acc1[nt], 0, 0, 0);
                const bf16x8 bM = *(const bf16x8*)((const char*)sWe +
                                   (((nrow << 9) + ((128 + kbase) << 1)) ^ swz));
                acc0[nt] = __builtin_amdgcn_mfma_f32_16x16x32_bf16(am0, bM, acc0[nt], 0, 0, 0);
                acc1[nt] = __builtin_amdgcn_mfma_f32_16x16x32_bf16(am1, bM, acc1[nt], 0, 0, 0);
            }
        }

        #pragma unroll
        for (int nt = 0; nt < 4; ++nt) {
            const int col = ch * 64 + nt * 16 + l15;
            #pragma unroll
            for (int r = 0; r < 4; ++r) {
                const int e0 = ebase + mp * 32 + (lg << 2) + r;
                const int e1 = e0 + 16;
                if (e0 < E) ebuf[(size_t)e0 * 128 + col] = f2bf(acc0[nt][r]);
                if (e1 < E) ebuf[(size_t)e1 * 128 + col] = f2bf(acc1[nt][r]);
            }
        }
        __syncthreads();   // before next tile's stage overwrites sMsg
    }
}

// ---------------------------------------------------------------------------
// CSR build
// ---------------------------------------------------------------------------
__global__ __launch_bounds__(256) void k_hist(
    const int* __restrict__ ei, int* __restrict__ counts, int E)
{
    int i = blockIdx.x * 256 + threadIdx.x;
    if (i < E) atomicAdd(&counts[ei[E + i]], 1);
}

__global__ __launch_bounds__(256) void k_scan_partial(
    const int* __restrict__ counts, int* __restrict__ partial, int N)
{
    const int base = blockIdx.x * SCAN_CHUNK;
    int v = 0;
    for (int i = threadIdx.x; i < SCAN_CHUNK; i += 256) {
        const int idx = base + i;
        if (idx < N) v += counts[idx];
    }
    __shared__ int red[4];
    #pragma unroll
    for (int off = 1; off < 64; off <<= 1) v += __shfl_xor(v, off);
    if ((threadIdx.x & 63) == 0) red[threadIdx.x >> 6] = v;
    __syncthreads();
    if (threadIdx.x == 0) partial[blockIdx.x] = red[0] + red[1] + red[2] + red[3];
}

__global__ __launch_bounds__(256) void k_scan_base(
    const int* __restrict__ partial, int* __restrict__ base, int nb)
{
    __shared__ int tmp[256];
    const int v = (threadIdx.x < nb) ? partial[threadIdx.x] : 0;
    tmp[threadIdx.x] = v;
    __syncthreads();
    for (int off = 1; off < 256; off <<= 1) {
        const int add = (threadIdx.x >= off) ? tmp[threadIdx.x - off] : 0;
        __syncthreads();
        tmp[threadIdx.x] += add;
        __syncthreads();
    }
    if (threadIdx.x < nb) base[threadIdx.x] = tmp[threadIdx.x] - v;
}

__global__ __launch_bounds__(256) void k_scan_final(
    const int* __restrict__ counts, const int* __restrict__ base,
    int* __restrict__ rowptr, int* __restrict__ cursor, int N)
{
    const int i0 = blockIdx.x * SCAN_CHUNK;
    __shared__ int tmp[256];
    const int ia = i0 + threadIdx.x * 2, ib = ia + 1;
    const int v0 = (ia < N) ? counts[ia] : 0;
    const int v1 = (ib < N) ? counts[ib] : 0;
    const int s = v0 + v1;
    tmp[threadIdx.x] = s;
    __syncthreads();
    for (int off = 1; off < 256; off <<= 1) {
        const int add = (threadIdx.x >= off) ? tmp[threadIdx.x - off] : 0;
        __syncthreads();
        tmp[threadIdx.x] += add;
        __syncthreads();
    }
    const int excl = tmp[threadIdx.x] - s + base[blockIdx.x];
    if (ia < N) { rowptr[ia] = excl;      cursor[ia] = excl; }
    if (ib < N) { rowptr[ib] = excl + v0; cursor[ib] = excl + v0; }
}

__global__ __launch_bounds__(256) void k_fill(
    const int* __restrict__ ei, const float* __restrict__ t,
    const float* __restrict__ lu, int* __restrict__ cursor,
    int* __restrict__ perm, int* __restrict__ srcp,
    float* __restrict__ relo, int E)
{
    int i = blockIdx.x * 256 + threadIdx.x;
    if (i < E) {
        const int s = ei[i];
        const int d = ei[E + i];
        const int pos = atomicAdd(&cursor[d], 1);
        perm[pos] = i;
        srcp[pos] = s;
        relo[i] = t[i] - lu[s];
    }
}

// ---------------------------------------------------------------------------
// K3 v5: fused aggregation, TWO dst per wave. Each 32-lane half owns one dst:
// half = l>>5, eg = (l>>4)&1 (2 edge groups of 16), s16 = l&15.
// 2 edges/iter per dst; chunk = 32 slots. Logit reduce per head = xor{1,2,4}
// within 8-lane head slices (unchanged); cross-group combine = xor16 only.
// shfl half-local with sources always active. Write-only output + bf16 skip.
// ---------------------------------------------------------------------------
__global__ __launch_bounds__(256) void k_agg(
    const int* __restrict__ srcp, const int* __restrict__ perm,
    const int* __restrict__ rowptr, const int* __restrict__ counts,
    const uint4* __restrict__ qb4, const uint4* __restrict__ kb4,
    const uint4* __restrict__ vb4, const uint4* __restrict__ eb4,
    const uint4* __restrict__ skb4, float4* __restrict__ out4, int N)
{
    const int tid = threadIdx.x;
    const int l = tid & 63;
    const int half = l >> 5;          // dst within the wave (0/1)
    const int l5 = l & 31;            // lane within half
    const int eg = l5 >> 4;           // edge group 0..1
    const int s16 = l & 15;           // 16B slot (8 channels)
    const int d = blockIdx.x * 8 + ((tid >> 6) << 1) + half;
    if (d >= N) return;
    const int start = rowptr[d];
    const int deg = counts[d];

    float qf[8];
    unpack8(qb4[(size_t)d * 16 + s16], qf);
    float accf[8] = {0.f, 0.f, 0.f, 0.f, 0.f, 0.f, 0.f, 0.f};
    float denom = 0.f;

    for (int cbase = 0; cbase < deg; cbase += 32) {
        const int clen = min(deg - cbase, 32);
        int mySrc = 0, myEid = 0;
        if (l5 < clen) {
            mySrc = srcp[start + cbase + l5];   // coalesced per half
            myEid = perm[start + cbase + l5];   // coalesced per half
        }

        #pragma unroll 2
        for (int i = 0; i < clen; i += 2) {
            const int off = i + eg;
            const bool valid = off < clen;
            const int offc = valid ? off : 0;
            // shfl sources are within this (active) half; all its lanes are
            // active here (chunk loop condition is half-uniform)
            const int src = __shfl(mySrc, (half << 5) + offc);
            const int eid = __shfl(myEid, (half << 5) + offc);
            if (valid) {                        // uniform per 16-lane group
                float kf[8], ef[8], vf[8];
                unpack8(kb4[(size_t)src * 16 + s16], kf);
                unpack8(eb4[(size_t)eid * 16 + s16], ef);
                unpack8(vb4[(size_t)src * 16 + s16], vf);
                float s = 0.f;
                #pragma unroll
                for (int j = 0; j < 8; ++j) s = fmaf(qf[j], kf[j] + ef[j], s);
                s += __shfl_xor(s, 1);
                s += __shfl_xor(s, 2);
                s += __shfl_xor(s, 4);          // per-head reduce (8 lanes)
                const float p = __expf(s * SCALE_ATTN);
                denom += p;
                #pragma unroll
                for (int j = 0; j < 8; ++j) accf[j] = fmaf(p, vf[j] + ef[j], accf[j]);
            }
        }
    }
    // combine the 2 edge groups within the half (bit 4)
    #pragma unroll
    for (int j = 0; j < 8; ++j) accf[j] += __shfl_xor(accf[j], 16);
    denom += __shfl_xor(denom, 16);

    if (l5 < 16) {
        const float inv = 1.f / (denom + 1e-16f);
        float sk[8];
        unpack8(skb4[(size_t)d * 16 + s16], sk);
        float4* o = out4 + (size_t)d * 32 + s16 * 2;
        o[0] = make_float4(fmaf(accf[0], inv, sk[0]), fmaf(accf[1], inv, sk[1]),
                           fmaf(accf[2], inv, sk[2]), fmaf(accf[3], inv, sk[3]));
        o[1] = make_float4(fmaf(accf[4], inv, sk[4]), fmaf(accf[5], inv, sk[5]),
                           fmaf(accf[6], inv, sk[6]), fmaf(accf[7], inv, sk[7]));
    }
}

// ---------------------------------------------------------------------------
extern "C" void kernel_launch(void* const* d_in, const int* in_sizes, int n_in,
                              void* d_out, int out_size, void* d_ws, size_t ws_size,
                              hipStream_t stream)
{
    const float* x   = (const float*)d_in[0];
    const float* lu  = (const float*)d_in[1];
    const int*   ei  = (const int*)d_in[2];
    const float* t   = (const float*)d_in[3];
    const float* msg = (const float*)d_in[4];
    const float* tw  = (const float*)d_in[5];
    const float* tb  = (const float*)d_in[6];
    const float* Wq  = (const float*)d_in[7];
    const float* bq  = (const float*)d_in[8];
    const float* Wk  = (const float*)d_in[9];
    const float* bk  = (const float*)d_in[10];
    const float* Wv  = (const float*)d_in[11];
    const float* bv  = (const float*)d_in[12];
    const float* We  = (const float*)d_in[13];
    const float* Wsk = (const float*)d_in[14];
    const float* bsk = (const float*)d_in[15];

    const int N = in_sizes[1];   // last_update: N elements
    const int E = in_sizes[3];   // t: E elements
    float* out = (float*)d_out;

    char* ws = (char*)d_ws;
    unsigned short* qb  = (unsigned short*)ws;  ws += (size_t)N * 128 * sizeof(unsigned short);
    unsigned short* kb  = (unsigned short*)ws;  ws += (size_t)N * 128 * sizeof(unsigned short);
    unsigned short* vb  = (unsigned short*)ws;  ws += (size_t)N * 128 * sizeof(unsigned short);
    unsigned short* skb = (unsigned short*)ws;  ws += (size_t)N * 128 * sizeof(unsigned short);
    unsigned short* eb  = (unsigned short*)ws;  ws += (size_t)E * 128 * sizeof(unsigned short);
    int*   counts  = (int*)ws;   ws += (size_t)N * sizeof(int);
    int*   rowptr  = (int*)ws;   ws += (size_t)N * sizeof(int);
    int*   cursor  = (int*)ws;   ws += (size_t)N * sizeof(int);
    int*   perm    = (int*)ws;   ws += (size_t)E * sizeof(int);
    int*   srcp    = (int*)ws;   ws += (size_t)E * sizeof(int);
    float* relo    = (float*)ws; ws += (size_t)E * sizeof(float);
    int*   partial = (int*)ws;   ws += 512 * sizeof(int);
    int*   baseArr = (int*)ws;   ws += 512 * sizeof(int);

    const int nScan = (N + SCAN_CHUNK - 1) / SCAN_CHUNK;

    const int n4 = (N + 3) / 4;
    k_zero<<<(n4 + 255) / 256, 256, 0, stream>>>((int4*)counts, n4);

    // CSR build
    k_hist<<<(E + 255) / 256, 256, 0, stream>>>(ei, counts, E);
    k_scan_partial<<<nScan, 256, 0, stream>>>(counts, partial, N);
    k_scan_base<<<1, 256, 0, stream>>>(partial, baseArr, nScan);
    k_scan_final<<<nScan, 256, 0, stream>>>(counts, baseArr, rowptr, cursor, N);
    k_fill<<<(E + 255) / 256, 256, 0, stream>>>(ei, t, lu, cursor, perm, srcp, relo, E);

    // node linears: q/k/v/skip (all bf16) in ONE staged-x launch
    const int nTN = (N + 31) / 32;
    k_node_mfma<<<min(nTN, 1024), 512, 0, stream>>>(
        (const float4*)x, Wq, Wk, Wv, Wsk, bq, bk, bv, bsk,
        qb, kb, vb, skb, N, nTN);

    // edge GEMM v4: 64-edge tiles, 4-wave blocks, B-reuse x2
    const int nTE = (E + 63) / 64;
    k_edge_mfma<<<min(nTE, 512), 256, 0, stream>>>(
        (const float4*)msg, relo,
        (const float4*)tw, (const float4*)tb, We, eb, E, nTE);

    // fused aggregation v5: 2 dst/wave, predicated loads, write-only output
    k_agg<<<(N + 7) / 8, 256, 0, stream>>>(
        srcp, perm, rowptr, counts,
        (const uint4*)qb, (const uint4*)kb, (const uint4*)vb, (const uint4*)eb,
        (const uint4*)skb, (float4*)out, N);
}